// Round 2
// baseline (2621.801 us; speedup 1.0000x reference)
//
#include <hip/hip_runtime.h>
#include <hip/hip_bf16.h>
#include <math.h>

#define NSMP 32768
#define NFR 128
#define NCH 1024
#define NB 4

// ---------------- STFT: one block per (batch, frame); 2048-pt radix-2 FFT in LDS ----------------
__global__ __launch_bounds__(256) void stft_kernel(const float* __restrict__ x,
                                                   float* __restrict__ h) {
  __shared__ float re[2048];
  __shared__ float im[2048];
  int bid = blockIdx.x;
  int b = bid >> 7;
  int f = bid & 127;
  int tid = threadIdx.x;
  const float TWO_PI = 6.28318530717958647692f;
  for (int i = tid; i < 2048; i += 256) {
    int rev = (int)(__brev((unsigned)i) >> 21);
    int pos = f * 256 + rev;
    float v = (pos < NSMP) ? x[b * NSMP + pos] : 0.f;
    float w = 0.5f - 0.5f * cosf(TWO_PI * (float)rev / 2047.0f);  // jnp.hanning(2048)
    re[i] = v * w;
    im[i] = 0.f;
  }
  __syncthreads();
  for (int s = 0; s < 11; ++s) {
    int half = 1 << s;
    for (int q = 0; q < 4; ++q) {
      int bi = tid + q * 256;
      int j = bi & (half - 1);
      int i0 = ((bi >> s) << (s + 1)) | j;
      int i1 = i0 + half;
      float ang = -3.14159265358979323846f * (float)j / (float)half;
      float sn, cs;
      sincosf(ang, &sn, &cs);
      float ur = re[i0], ui = im[i0];
      float vr = re[i1], vi = im[i1];
      float tr = vr * cs - vi * sn;
      float ti = vr * sn + vi * cs;
      re[i0] = ur + tr; im[i0] = ui + ti;
      re[i1] = ur - tr; im[i1] = ui - ti;
    }
    __syncthreads();
  }
  for (int k = tid; k < 1024; k += 256) {
    float m = sqrtf(re[k] * re[k] + im[k] * im[k]);
    h[(b * NCH + k) * NFR + f] = m;  // already transposed: (b, ch=bin, t=frame)
  }
}

// ---------------- dilated residual conv layer: h += lrelu(W0 h(t) + W1 h(t+D) + b) ----------------
template <int D>
__global__ __launch_bounds__(256) void conv_kernel(const float* __restrict__ hin,
                                                   float* __restrict__ hout,
                                                   const float* __restrict__ w,
                                                   const float* __restrict__ bias) {
  __shared__ float Hs[32][192];   // 32 input ch x (128 + up-to-64 future pad, zeros)
  __shared__ float W0s[32][8];
  __shared__ float W1s[32][8];
  int ot = blockIdx.x;            // 128 tiles of 8 output channels
  int b = blockIdx.y;
  int tid = threadIdx.x;
  int o_l = tid & 7;
  int tg = tid >> 3;              // 32 groups of 4 time steps
  int t0 = tg * 4;
  int og = ot * 8;
  const float* hb = hin + b * NCH * NFR;
  float acc0 = 0.f, acc1 = 0.f, acc2 = 0.f, acc3 = 0.f;
  for (int cc = 0; cc < 32; ++cc) {
    int c0 = cc * 32;
    __syncthreads();
    for (int idx = tid; idx < 32 * 192; idx += 256) {
      int c = idx / 192;
      int col = idx - c * 192;
      Hs[c][col] = (col < NFR) ? hb[(c0 + c) * NFR + col] : 0.f;
    }
    for (int idx = tid; idx < 512; idx += 256) {
      int o = idx >> 6;
      int c = (idx >> 1) & 31;
      int k = idx & 1;
      float wv = w[((og + o) * NCH + (c0 + c)) * 2 + k];
      if (k == 0) W0s[c][o] = wv; else W1s[c][o] = wv;
    }
    __syncthreads();
#pragma unroll 4
    for (int c = 0; c < 32; ++c) {
      float w0 = W0s[c][o_l];
      float w1 = W1s[c][o_l];
      acc0 += w0 * Hs[c][t0 + 0] + w1 * Hs[c][t0 + 0 + D];
      acc1 += w0 * Hs[c][t0 + 1] + w1 * Hs[c][t0 + 1 + D];
      acc2 += w0 * Hs[c][t0 + 2] + w1 * Hs[c][t0 + 2 + D];
      acc3 += w0 * Hs[c][t0 + 3] + w1 * Hs[c][t0 + 3 + D];
    }
  }
  float bv = bias[og + o_l];
  int off = (b * NCH + og + o_l) * NFR + t0;
  float a[4] = {acc0, acc1, acc2, acc3};
#pragma unroll
  for (int i = 0; i < 4; ++i) {
    float v = a[i] + bv;
    v = (v > 0.f) ? v : 0.2f * v;
    hout[off + i] = hin[off + i] + v;
  }
}

// ---------------- enc = up_w @ h + up_b : (B,256,128) ----------------
__global__ __launch_bounds__(256) void enc_kernel(const float* __restrict__ h,
                                                  const float* __restrict__ upw,
                                                  const float* __restrict__ upb,
                                                  float* __restrict__ enc) {
  __shared__ float Hs[32][128];
  __shared__ float Wsh[32][4];
  int ot = blockIdx.x;   // 64 tiles of 4 outputs
  int b = blockIdx.y;
  int tid = threadIdx.x;
  int o_l = tid & 3;
  int tg = tid >> 2;     // 64 groups of 2 t
  int t0 = tg * 2;
  int og = ot * 4;
  const float* hb = h + b * NCH * NFR;
  float acc0 = 0.f, acc1 = 0.f;
  for (int cc = 0; cc < 32; ++cc) {
    int c0 = cc * 32;
    __syncthreads();
    for (int idx = tid; idx < 4096; idx += 256) {
      int c = idx >> 7;
      int col = idx & 127;
      Hs[c][col] = hb[(c0 + c) * NFR + col];
    }
    if (tid < 128) {
      int o = tid >> 5;
      int c = tid & 31;
      Wsh[c][o] = upw[(og + o) * NCH + c0 + c];
    }
    __syncthreads();
#pragma unroll 4
    for (int c = 0; c < 32; ++c) {
      float wv = Wsh[c][o_l];
      acc0 += wv * Hs[c][t0];
      acc1 += wv * Hs[c][t0 + 1];
    }
  }
  float bv = upb[og + o_l];
  enc[(b * 256 + og + o_l) * NFR + t0] = acc0 + bv;
  enc[(b * 256 + og + o_l) * NFR + t0 + 1] = acc1 + bv;
}

// ---------------- z-mean, dense latent, unit-norm, room & mix MLP heads ----------------
__global__ __launch_bounds__(256) void dense_mlp_kernel(
    const float* __restrict__ h,
    const float* __restrict__ latw, const float* __restrict__ latb,
    const float* __restrict__ rw, const float* __restrict__ rb,
    const float* __restrict__ rg, const float* __restrict__ rbe,
    const float* __restrict__ rowt, const float* __restrict__ rob,
    const float* __restrict__ mw, const float* __restrict__ mb,
    const float* __restrict__ mg, const float* __restrict__ mbe,
    const float* __restrict__ mow, const float* __restrict__ mob,
    float* __restrict__ room, float* __restrict__ mixv) {
  __shared__ float z[1024];
  int b = blockIdx.x;
  int tid = threadIdx.x;
  const float* hb = h + b * NCH * NFR;
  for (int c = tid; c < 1024; c += 256) {
    float s = 0.f;
    const float* r = hb + c * NFR;
#pragma unroll 8
    for (int t = 0; t < NFR; ++t) s += r[t];
    z[c] = s * (1.f / 128.f);
  }
  __syncthreads();
  if (tid >= 64) return;   // one wave does the tiny MLPs; no barriers below
  int j = tid & 15;
  int p = tid >> 4;        // 4 partial-sum groups
  float dsum = 0.f;
  for (int c = p * 256; c < p * 256 + 256; ++c)
    dsum += z[c] * latw[c * 16 + j];
  dsum += __shfl_xor(dsum, 16);
  dsum += __shfl_xor(dsum, 32);
  float dj = dsum + latb[j];
  float sq = dj * dj;
  sq += __shfl_xor(sq, 1, 16);
  sq += __shfl_xor(sq, 2, 16);
  sq += __shfl_xor(sq, 4, 16);
  sq += __shfl_xor(sq, 8, 16);
  float a = dj / (sqrtf(sq) + 1e-8f);   // unit_norm(dense)

  const float* W = rw;  const float* Bb = rb;
  const float* G = rg;  const float* Be = rbe;
  for (int which = 0; which < 2; ++which) {
    float v = a;
    for (int l = 0; l < 3; ++l) {
      float accv = Bb[l * 16 + j];
      for (int k = 0; k < 16; ++k) {
        float ak = __shfl(v, (tid & 48) | k);
        accv += ak * W[(l * 16 + k) * 16 + j];
      }
      float mu = accv;
      mu += __shfl_xor(mu, 1, 16); mu += __shfl_xor(mu, 2, 16);
      mu += __shfl_xor(mu, 4, 16); mu += __shfl_xor(mu, 8, 16);
      mu *= (1.f / 16.f);
      float dv = accv - mu;
      float var = dv * dv;
      var += __shfl_xor(var, 1, 16); var += __shfl_xor(var, 2, 16);
      var += __shfl_xor(var, 4, 16); var += __shfl_xor(var, 8, 16);
      var *= (1.f / 16.f);
      float xn = dv * rsqrtf(var + 1e-5f) * G[l * 16 + j] + Be[l * 16 + j];
      v = (xn > 0.f) ? xn : 0.2f * xn;
    }
    if (which == 0) {
      int r = tid & 7;
      float logit = rob[r];
      for (int k = 0; k < 16; ++k) {
        float ak = __shfl(v, (tid & 48) | k);
        logit += ak * rowt[k * 8 + r];
      }
      float mx = logit;
      mx = fmaxf(mx, __shfl_xor(mx, 1, 8));
      mx = fmaxf(mx, __shfl_xor(mx, 2, 8));
      mx = fmaxf(mx, __shfl_xor(mx, 4, 8));
      float e = expf(logit - mx);
      float se = e;
      se += __shfl_xor(se, 1, 8);
      se += __shfl_xor(se, 2, 8);
      se += __shfl_xor(se, 4, 8);
      if (tid < 8) room[b * 8 + r] = e / se;
      W = mw; Bb = mb; G = mg; Be = mbe;
    } else {
      float logit = mob[0];
      for (int k = 0; k < 16; ++k) {
        float ak = __shfl(v, (tid & 48) | k);
        logit += ak * mow[k];
      }
      if (tid == 0) mixv[b] = 1.f / (1.f + expf(-logit));
    }
  }
}

// ---------------- top-16 over enc (jax tie semantics: lower flat index wins) ----------------
__global__ __launch_bounds__(256) void topk_kernel(const float* __restrict__ enc,
                                                   float* __restrict__ vals,
                                                   int* __restrict__ chs,
                                                   int* __restrict__ tps) {
  __shared__ float cv[4096];
  __shared__ int ci[4096];
  __shared__ float rv[256];
  __shared__ int ri[256];
  int b = blockIdx.x;
  int tid = threadIdx.x;
  const float* e = enc + b * 32768;
  float lv[16];
  int li[16];
#pragma unroll
  for (int q = 0; q < 16; ++q) { lv[q] = -INFINITY; li[q] = 0x7fffffff; }
  for (int i = tid; i < 32768; i += 256) {
    float v = e[i];
    if ((v > lv[0]) || (v == lv[0] && i < li[0])) {
      int q = 0;
      while (q < 15) {
        float nv = lv[q + 1]; int ni = li[q + 1];
        if (!((v > nv) || (v == nv && i < ni))) break;
        lv[q] = nv; li[q] = ni;
        ++q;
      }
      lv[q] = v; li[q] = i;
    }
  }
  for (int q = 0; q < 16; ++q) { cv[tid * 16 + q] = lv[q]; ci[tid * 16 + q] = li[q]; }
  __syncthreads();
  for (int round = 0; round < 16; ++round) {
    float bv = -INFINITY; int bi = 0x7fffffff; int bq = 0;
#pragma unroll
    for (int q = 0; q < 16; ++q) {
      float v = cv[tid * 16 + q]; int ii = ci[tid * 16 + q];
      if ((v > bv) || (v == bv && ii < bi)) { bv = v; bi = ii; bq = q; }
    }
    rv[tid] = bv; ri[tid] = bi;
    __syncthreads();
    for (int off = 128; off > 0; off >>= 1) {
      if (tid < off) {
        float v2 = rv[tid + off]; int i2 = ri[tid + off];
        if ((v2 > rv[tid]) || (v2 == rv[tid] && i2 < ri[tid])) { rv[tid] = v2; ri[tid] = i2; }
      }
      __syncthreads();
    }
    float wvv = rv[0]; int wi = ri[0];
    if (tid == 0) {
      // negative winners: the reference's top_k would instead pick a zero entry of `full`
      // (value 0 -> zero event). Clamp value to 0 so the event contributes nothing.
      vals[b * 16 + round] = (wvv > 0.f) ? wvv : 0.f;
      chs[b * 16 + round] = wi >> 7;            // i = ch*128 + t
      tps[b * 16 + round] = (wi & 127) * 256;   // sample position t*STEP
    }
    if (bi == wi) { cv[tid * 16 + bq] = -INFINITY; ci[tid * 16 + bq] = 0x7fffffff; }
    __syncthreads();
  }
}

// ---------------- dry = sum of 16 scaled shifted atoms (sparse conv collapsed) ----------------
__global__ void dry_kernel(const float* __restrict__ atoms,
                           const float* __restrict__ vals, const int* __restrict__ chs,
                           const int* __restrict__ tps, float* __restrict__ dry) {
  int b = blockIdx.y;
  int n = blockIdx.x * 256 + threadIdx.x;
  float acc = 0.f;
#pragma unroll 4
  for (int j = 0; j < 16; ++j) {
    float v = vals[b * 16 + j];
    int tp = tps[b * 16 + j];
    int ch = chs[b * 16 + j];
    if (v != 0.f && n >= tp)
      acc += v * atoms[(size_t)ch * NSMP + (n - tp)];
  }
  dry[b * NSMP + n] = acc;
}

// ---------------- impulse = room @ impulses ----------------
__global__ void impulse_kernel(const float* __restrict__ imps,
                               const float* __restrict__ room, float* __restrict__ imp) {
  int b = blockIdx.y;
  int n = blockIdx.x * 256 + threadIdx.x;
  float acc = 0.f;
#pragma unroll
  for (int r = 0; r < 8; ++r)
    acc += room[b * 8 + r] * imps[r * NSMP + n];
  imp[b * NSMP + n] = acc;
}

// ---------------- wet = causal direct convolution dry (*) impulse, split-m + atomics ----------------
__global__ __launch_bounds__(256) void wet_kernel(const float* __restrict__ dry,
                                                  const float* __restrict__ impulse,
                                                  float* __restrict__ wet) {
  int g = blockIdx.x;    // m-group (8 chunks of 256 m each)
  int nt = blockIdx.y;   // n-tile of 2048
  int b = blockIdx.z;
  if (g > nt) return;    // entire m-group beyond the causal triangle
  __shared__ float ds[256];
  __shared__ float is[2568];
  int tid = threadIdx.x;
  int n0 = nt * 2048;
  float acc[8] = {0, 0, 0, 0, 0, 0, 0, 0};
  int cbeg = g * 8;
  int cend = min(g * 8 + 8, 8 * nt + 8);
  for (int c = cbeg; c < cend; ++c) {
    int m0 = c * 256;
    int base = n0 - m0 - 256;
    __syncthreads();
    ds[tid] = dry[b * NSMP + m0 + tid];
    for (int k = tid; k < 2568; k += 256) {
      int idx = base + k;
      is[k] = (idx >= 0 && idx < NSMP) ? impulse[b * NSMP + idx] : 0.f;
    }
    __syncthreads();
    float wv[8];
    int kb = tid * 8 + 1;
#pragma unroll
    for (int i = 0; i < 8; ++i) wv[i] = is[kb + i];
#pragma unroll 8
    for (int step = 0; step < 256; ++step) {
      float dv = ds[255 - step];
#pragma unroll
      for (int i = 0; i < 8; ++i) acc[i] += dv * wv[i];
#pragma unroll
      for (int i = 0; i < 7; ++i) wv[i] = wv[i + 1];
      wv[7] = is[kb + 8 + step];
    }
  }
#pragma unroll
  for (int i = 0; i < 8; ++i)
    atomicAdd(&wet[b * NSMP + n0 + tid * 8 + i], acc[i]);
}

// ---------------- out = dry*mix + wet*(1-mix) ----------------
__global__ void out_kernel(const float* __restrict__ dry, const float* __restrict__ wet,
                           const float* __restrict__ mixv, float* __restrict__ out) {
  int b = blockIdx.y;
  int n = blockIdx.x * 256 + threadIdx.x;
  float m = mixv[b];
  float v = dry[b * NSMP + n] * m + wet[b * NSMP + n] * (1.f - m);
  out[b * NSMP + n] = v;
}

extern "C" void kernel_launch(void* const* d_in, const int* in_sizes, int n_in,
                              void* d_out, int out_size, void* d_ws, size_t ws_size,
                              hipStream_t stream) {
  const float* x    = (const float*)d_in[0];
  const float* atoms= (const float*)d_in[1];
  const float* encw = (const float*)d_in[2];
  const float* encb = (const float*)d_in[3];
  const float* upw  = (const float*)d_in[4];
  const float* upb  = (const float*)d_in[5];
  const float* latw = (const float*)d_in[6];
  const float* latb = (const float*)d_in[7];
  const float* rw   = (const float*)d_in[8];
  const float* rb   = (const float*)d_in[9];
  const float* rg   = (const float*)d_in[10];
  const float* rbe  = (const float*)d_in[11];
  const float* rowt = (const float*)d_in[12];
  const float* rob  = (const float*)d_in[13];
  const float* mw   = (const float*)d_in[14];
  const float* mb   = (const float*)d_in[15];
  const float* mg   = (const float*)d_in[16];
  const float* mbe  = (const float*)d_in[17];
  const float* mow  = (const float*)d_in[18];
  const float* mob  = (const float*)d_in[19];
  const float* imps = (const float*)d_in[20];

  float* f    = (float*)d_ws;
  float* h0   = f;                 // 524288
  float* h1   = f + 524288;        // 524288
  float* enc  = f + 1048576;       // 131072
  float* dry  = f + 1179648;       // 131072
  float* imp  = f + 1310720;       // 131072
  float* wet  = f + 1441792;       // 131072
  float* room = f + 1572864;       // 32
  float* mixv = f + 1572896;       // 4
  float* vals = f + 1572928;       // 64
  int*   chs  = (int*)(f + 1572992);
  int*   tps  = (int*)(f + 1573056);

  stft_kernel<<<512, 256, 0, stream>>>(x, h0);

  const int dil[8] = {1, 2, 4, 8, 16, 32, 64, 1};
  float* bufs[2] = {h0, h1};
  for (int l = 0; l < 8; ++l) {
    const float* hin = bufs[l & 1];
    float* hout = bufs[(l + 1) & 1];
    const float* wl = encw + (size_t)l * 1024 * 1024 * 2;
    const float* bl = encb + l * 1024;
    dim3 gs(128, 4);
    switch (dil[l]) {
      case 1:  conv_kernel<1><<<gs, 256, 0, stream>>>(hin, hout, wl, bl); break;
      case 2:  conv_kernel<2><<<gs, 256, 0, stream>>>(hin, hout, wl, bl); break;
      case 4:  conv_kernel<4><<<gs, 256, 0, stream>>>(hin, hout, wl, bl); break;
      case 8:  conv_kernel<8><<<gs, 256, 0, stream>>>(hin, hout, wl, bl); break;
      case 16: conv_kernel<16><<<gs, 256, 0, stream>>>(hin, hout, wl, bl); break;
      case 32: conv_kernel<32><<<gs, 256, 0, stream>>>(hin, hout, wl, bl); break;
      case 64: conv_kernel<64><<<gs, 256, 0, stream>>>(hin, hout, wl, bl); break;
    }
  }
  // 8 layers of ping-pong: final h lives in h0

  dense_mlp_kernel<<<4, 256, 0, stream>>>(h0, latw, latb, rw, rb, rg, rbe, rowt, rob,
                                          mw, mb, mg, mbe, mow, mob, room, mixv);
  enc_kernel<<<dim3(64, 4), 256, 0, stream>>>(h0, upw, upb, enc);
  topk_kernel<<<4, 256, 0, stream>>>(enc, vals, chs, tps);
  dry_kernel<<<dim3(128, 4), 256, 0, stream>>>(atoms, vals, chs, tps, dry);
  impulse_kernel<<<dim3(128, 4), 256, 0, stream>>>(imps, room, imp);
  hipMemsetAsync(wet, 0, (size_t)NB * NSMP * sizeof(float), stream);
  wet_kernel<<<dim3(16, 16, 4), 256, 0, stream>>>(dry, imp, wet);
  out_kernel<<<dim3(128, 4), 256, 0, stream>>>(dry, wet, mixv, (float*)d_out);
}

// Round 4
// 1571.878 us; speedup vs baseline: 1.6679x; 1.6679x over previous
//
#include <hip/hip_runtime.h>
#include <hip/hip_bf16.h>
#include <math.h>

#define NSMP 32768
#define NFR 128
#define NCH 1024
#define NB 4

// ---------------- STFT: one block per (batch, frame); 2048-pt radix-2 FFT in LDS ----------------
__global__ __launch_bounds__(256) void stft_kernel(const float* __restrict__ x,
                                                   float* __restrict__ h) {
  __shared__ float re[2048];
  __shared__ float im[2048];
  int bid = blockIdx.x;
  int b = bid >> 7;
  int f = bid & 127;
  int tid = threadIdx.x;
  const float TWO_PI = 6.28318530717958647692f;
  for (int i = tid; i < 2048; i += 256) {
    int rev = (int)(__brev((unsigned)i) >> 21);
    int pos = f * 256 + rev;
    float v = (pos < NSMP) ? x[b * NSMP + pos] : 0.f;
    float w = 0.5f - 0.5f * cosf(TWO_PI * (float)rev / 2047.0f);  // jnp.hanning(2048)
    re[i] = v * w;
    im[i] = 0.f;
  }
  __syncthreads();
  for (int s = 0; s < 11; ++s) {
    int half = 1 << s;
    for (int q = 0; q < 4; ++q) {
      int bi = tid + q * 256;
      int j = bi & (half - 1);
      int i0 = ((bi >> s) << (s + 1)) | j;
      int i1 = i0 + half;
      float ang = -3.14159265358979323846f * (float)j / (float)half;
      float sn, cs;
      sincosf(ang, &sn, &cs);
      float ur = re[i0], ui = im[i0];
      float vr = re[i1], vi = im[i1];
      float tr = vr * cs - vi * sn;
      float ti = vr * sn + vi * cs;
      re[i0] = ur + tr; im[i0] = ui + ti;
      re[i1] = ur - tr; im[i1] = ui - ti;
    }
    __syncthreads();
  }
  for (int k = tid; k < 1024; k += 256) {
    float m = sqrtf(re[k] * re[k] + im[k] * im[k]);
    h[(b * NCH + k) * NFR + f] = m;  // already transposed: (b, ch=bin, t=frame)
  }
}

// ---------------- f32 register-tiled GEMM partial, K-split, atomicAdd into yacc ----------------
// y[o,t] += sum_{k in slice} W[o][k] * B[k][t]
//   TAPS==2: k=2c+tap, B[k][t] = h[c][t+tap*D] (0 past NFR)   TAPS==1: B[k][t] = h[k][t]
// Block: 64 o x 128 t (one batch), K-slice KTOT/SPLIT. 256 thr, 4x8 acc/thread.
template <int TAPS, int D, int KTOT, int SPLIT>
__global__ __launch_bounds__(256) void gemm_partial(const float* __restrict__ hin,
                                                    const float* __restrict__ W,
                                                    float* __restrict__ yacc,
                                                    int MROWS) {
  __shared__ float As[64][68];   // [k][o], stride 68 keeps b128 reads 16B-aligned
  __shared__ float Bs[64][132];  // [k][t]
  int tid = threadIdx.x;
  int og = blockIdx.x * 64;
  int s = blockIdx.y;
  int b = blockIdx.z;
  int k_begin = s * (KTOT / SPLIT);
  const int KSTEPS = (KTOT / SPLIT) / 64;
  const float* hb = hin + (size_t)b * (NCH * NFR);
  int to = tid & 15;   // owns o = og + to*4 + {0..3}
  int tt = tid >> 4;   // owns t = tt*8 + {0..7}

  float acc[4][8] = {};

  for (int ks = 0; ks < KSTEPS; ++ks) {
    int k0 = k_begin + ks * 64;
    __syncthreads();
    // ---- stage A transposed: As[kk][o] = W[og+o][k0+kk] ----
    {
      int rr = tid >> 2;
      int cs = (tid & 3) * 16;
      const float4* src = (const float4*)(W + (size_t)(og + rr) * KTOT + k0 + cs);
#pragma unroll
      for (int q = 0; q < 4; ++q) {
        float4 v = src[q];
        As[cs + q * 4 + 0][rr] = v.x;
        As[cs + q * 4 + 1][rr] = v.y;
        As[cs + q * 4 + 2][rr] = v.z;
        As[cs + q * 4 + 3][rr] = v.w;
      }
    }
    // ---- stage B (pre-shifted taps): Bs[kk][t] ----
    {
      int r = tid >> 2;
      int tq = (tid & 3) * 32;
      if (TAPS == 2) {
        int c = (k0 >> 1) + (r >> 1);
        int sh = (r & 1) * D;
        const float* src = hb + (size_t)c * NFR + sh;
#pragma unroll
        for (int q = 0; q < 8; ++q) {
          int t0 = tq + q * 4;
          float4 v;
          v.x = (t0 + 0 + sh < NFR) ? src[t0 + 0] : 0.f;
          v.y = (t0 + 1 + sh < NFR) ? src[t0 + 1] : 0.f;
          v.z = (t0 + 2 + sh < NFR) ? src[t0 + 2] : 0.f;
          v.w = (t0 + 3 + sh < NFR) ? src[t0 + 3] : 0.f;
          *(float4*)&Bs[r][t0] = v;
        }
      } else {
        int c = k0 + r;
        const float4* src = (const float4*)(hb + (size_t)c * NFR + tq);
#pragma unroll
        for (int q = 0; q < 8; ++q) *(float4*)&Bs[r][tq + q * 4] = src[q];
      }
    }
    __syncthreads();
    // ---- inner: 3 x b128 LDS reads + 32 FMA per kk ----
#pragma unroll 4
    for (int kk = 0; kk < 64; ++kk) {
      float4 a = *(const float4*)&As[kk][to * 4];
      float4 b0 = *(const float4*)&Bs[kk][tt * 8];
      float4 b1 = *(const float4*)&Bs[kk][tt * 8 + 4];
      float av[4] = {a.x, a.y, a.z, a.w};
      float bv[8] = {b0.x, b0.y, b0.z, b0.w, b1.x, b1.y, b1.z, b1.w};
#pragma unroll
      for (int i = 0; i < 4; ++i)
#pragma unroll
        for (int j = 0; j < 8; ++j)
          acc[i][j] += av[i] * bv[j];
    }
  }
#pragma unroll
  for (int i = 0; i < 4; ++i)
#pragma unroll
    for (int j = 0; j < 8; ++j)
      atomicAdd(&yacc[((size_t)b * MROWS + og + to * 4 + i) * NFR + tt * 8 + j], acc[i][j]);
}

// ---------------- epilogue: hout = hin + lrelu(yacc + bias); yacc self-cleans to 0 ----------------
__global__ __launch_bounds__(256) void conv_epilogue(float* __restrict__ yacc,
                                                     const float* __restrict__ hin,
                                                     const float* __restrict__ bias,
                                                     float* __restrict__ hout) {
  int idx = blockIdx.x * 256 + threadIdx.x;  // float4 index, 131072 total
  int flat = idx * 4;
  int o = (flat >> 7) & 1023;
  float4 y = ((const float4*)yacc)[idx];
  float4 hv = ((const float4*)hin)[idx];
  float bv = bias[o];
  float4 r;
  float v;
  v = y.x + bv; r.x = hv.x + ((v > 0.f) ? v : 0.2f * v);
  v = y.y + bv; r.y = hv.y + ((v > 0.f) ? v : 0.2f * v);
  v = y.z + bv; r.z = hv.z + ((v > 0.f) ? v : 0.2f * v);
  v = y.w + bv; r.w = hv.w + ((v > 0.f) ? v : 0.2f * v);
  ((float4*)hout)[idx] = r;
  ((float4*)yacc)[idx] = (float4){0.f, 0.f, 0.f, 0.f};
}

// ---------------- z-mean, dense latent, unit-norm, room & mix MLP heads ----------------
__global__ __launch_bounds__(256) void dense_mlp_kernel(
    const float* __restrict__ h,
    const float* __restrict__ latw, const float* __restrict__ latb,
    const float* __restrict__ rw, const float* __restrict__ rb,
    const float* __restrict__ rg, const float* __restrict__ rbe,
    const float* __restrict__ rowt, const float* __restrict__ rob,
    const float* __restrict__ mw, const float* __restrict__ mb,
    const float* __restrict__ mg, const float* __restrict__ mbe,
    const float* __restrict__ mow, const float* __restrict__ mob,
    float* __restrict__ room, float* __restrict__ mixv) {
  __shared__ float z[1024];
  int b = blockIdx.x;
  int tid = threadIdx.x;
  const float* hb = h + b * NCH * NFR;
  for (int c = tid; c < 1024; c += 256) {
    float s = 0.f;
    const float* r = hb + c * NFR;
#pragma unroll 8
    for (int t = 0; t < NFR; ++t) s += r[t];
    z[c] = s * (1.f / 128.f);
  }
  __syncthreads();
  if (tid >= 64) return;   // one wave does the tiny MLPs; no barriers below
  int j = tid & 15;
  int p = tid >> 4;        // 4 partial-sum groups
  float dsum = 0.f;
  for (int c = p * 256; c < p * 256 + 256; ++c)
    dsum += z[c] * latw[c * 16 + j];
  dsum += __shfl_xor(dsum, 16);
  dsum += __shfl_xor(dsum, 32);
  float dj = dsum + latb[j];
  float sq = dj * dj;
  sq += __shfl_xor(sq, 1, 16);
  sq += __shfl_xor(sq, 2, 16);
  sq += __shfl_xor(sq, 4, 16);
  sq += __shfl_xor(sq, 8, 16);
  float a = dj / (sqrtf(sq) + 1e-8f);   // unit_norm(dense)

  const float* W = rw;  const float* Bb = rb;
  const float* G = rg;  const float* Be = rbe;
  for (int which = 0; which < 2; ++which) {
    float v = a;
    for (int l = 0; l < 3; ++l) {
      float accv = Bb[l * 16 + j];
      for (int k = 0; k < 16; ++k) {
        float ak = __shfl(v, (tid & 48) | k);
        accv += ak * W[(l * 16 + k) * 16 + j];
      }
      float mu = accv;
      mu += __shfl_xor(mu, 1, 16); mu += __shfl_xor(mu, 2, 16);
      mu += __shfl_xor(mu, 4, 16); mu += __shfl_xor(mu, 8, 16);
      mu *= (1.f / 16.f);
      float dv = accv - mu;
      float var = dv * dv;
      var += __shfl_xor(var, 1, 16); var += __shfl_xor(var, 2, 16);
      var += __shfl_xor(var, 4, 16); var += __shfl_xor(var, 8, 16);
      var *= (1.f / 16.f);
      float xn = dv * rsqrtf(var + 1e-5f) * G[l * 16 + j] + Be[l * 16 + j];
      v = (xn > 0.f) ? xn : 0.2f * xn;
    }
    if (which == 0) {
      int r = tid & 7;
      float logit = rob[r];
      for (int k = 0; k < 16; ++k) {
        float ak = __shfl(v, (tid & 48) | k);
        logit += ak * rowt[k * 8 + r];
      }
      float mx = logit;
      mx = fmaxf(mx, __shfl_xor(mx, 1, 8));
      mx = fmaxf(mx, __shfl_xor(mx, 2, 8));
      mx = fmaxf(mx, __shfl_xor(mx, 4, 8));
      float e = expf(logit - mx);
      float se = e;
      se += __shfl_xor(se, 1, 8);
      se += __shfl_xor(se, 2, 8);
      se += __shfl_xor(se, 4, 8);
      if (tid < 8) room[b * 8 + r] = e / se;
      W = mw; Bb = mb; G = mg; Be = mbe;
    } else {
      float logit = mob[0];
      for (int k = 0; k < 16; ++k) {
        float ak = __shfl(v, (tid & 48) | k);
        logit += ak * mow[k];
      }
      if (tid == 0) mixv[b] = 1.f / (1.f + expf(-logit));
    }
  }
}

// ---------------- top-16 (jax tie semantics): register lists + shuffle merge ----------------
// reads enc accumulator (+ per-channel bias), self-cleans accumulator to 0
__global__ __launch_bounds__(256) void topk_kernel(float* __restrict__ encacc,
                                                   const float* __restrict__ upb,
                                                   float* __restrict__ vals,
                                                   int* __restrict__ chs,
                                                   int* __restrict__ tps) {
  __shared__ float swv[4];
  __shared__ int swi[4];
  int b = blockIdx.x;
  int tid = threadIdx.x;
  float* e = encacc + b * 32768;
  float lv[16];
  int li[16];
#pragma unroll
  for (int q = 0; q < 16; ++q) { lv[q] = -INFINITY; li[q] = 0x7fffffff; }
  for (int i = tid; i < 32768; i += 256) {
    float v = e[i] + upb[i >> 7];
    e[i] = 0.f;  // self-clean for next call
    if (v > lv[15]) {
      float cv = v; int ci = i;
#pragma unroll
      for (int q = 0; q < 16; ++q) {
        if (cv > lv[q]) {
          float tv = lv[q]; int ti = li[q];
          lv[q] = cv; li[q] = ci;
          cv = tv; ci = ti;
        }
      }
    }
  }
  for (int round = 0; round < 16; ++round) {
    float cv = lv[0];
    int ci = li[0];
#pragma unroll
    for (int off = 1; off < 64; off <<= 1) {
      float ov = __shfl_xor(cv, off);
      int oi = __shfl_xor(ci, off);
      if (ov > cv || (ov == cv && oi < ci)) { cv = ov; ci = oi; }
    }
    if ((tid & 63) == 0) { swv[tid >> 6] = cv; swi[tid >> 6] = ci; }
    __syncthreads();
    float wv = swv[0]; int wi = swi[0];
#pragma unroll
    for (int w = 1; w < 4; ++w) {
      float v2 = swv[w]; int i2 = swi[w];
      if (v2 > wv || (v2 == wv && i2 < wi)) { wv = v2; wi = i2; }
    }
    if (tid == 0) {
      // negative winner: reference's top_k picks a zero of `full` instead -> zero event
      vals[b * 16 + round] = (wv > 0.f) ? wv : 0.f;
      chs[b * 16 + round] = wi >> 7;            // i = ch*128 + t
      tps[b * 16 + round] = (wi & 127) * 256;   // sample position t*STEP
    }
    if (li[0] == wi) {  // unique owner pops
#pragma unroll
      for (int q = 0; q < 15; ++q) { lv[q] = lv[q + 1]; li[q] = li[q + 1]; }
      lv[15] = -INFINITY; li[15] = 0x7fffffff;
    }
    __syncthreads();
  }
}

// ---------------- dry = sum of 16 scaled shifted atoms (sparse conv collapsed) ----------------
__global__ void dry_kernel(const float* __restrict__ atoms,
                           const float* __restrict__ vals, const int* __restrict__ chs,
                           const int* __restrict__ tps, float* __restrict__ dry) {
  int b = blockIdx.y;
  int n = blockIdx.x * 256 + threadIdx.x;
  float acc = 0.f;
#pragma unroll 4
  for (int j = 0; j < 16; ++j) {
    float v = vals[b * 16 + j];
    int tp = tps[b * 16 + j];
    int ch = chs[b * 16 + j];
    if (v != 0.f && n >= tp)
      acc += v * atoms[(size_t)ch * NSMP + (n - tp)];
  }
  dry[b * NSMP + n] = acc;
}

// ---------------- impulse = room @ impulses ----------------
__global__ void impulse_kernel(const float* __restrict__ imps,
                               const float* __restrict__ room, float* __restrict__ imp) {
  int b = blockIdx.y;
  int n = blockIdx.x * 256 + threadIdx.x;
  float acc = 0.f;
#pragma unroll
  for (int r = 0; r < 8; ++r)
    acc += room[b * 8 + r] * imps[r * NSMP + n];
  imp[b * NSMP + n] = acc;
}

// ---------------- wet = causal direct convolution dry (*) impulse, split-m + atomics ----------------
__global__ __launch_bounds__(256) void wet_kernel(const float* __restrict__ dry,
                                                  const float* __restrict__ impulse,
                                                  float* __restrict__ wet) {
  int g = blockIdx.x;    // m-group (8 chunks of 256 m each)
  int nt = blockIdx.y;   // n-tile of 2048
  int b = blockIdx.z;
  if (g > nt) return;    // entire m-group beyond the causal triangle
  __shared__ float ds[256];
  __shared__ float is[2568];
  int tid = threadIdx.x;
  int n0 = nt * 2048;
  float acc[8] = {0, 0, 0, 0, 0, 0, 0, 0};
  int cbeg = g * 8;
  int cend = min(g * 8 + 8, 8 * nt + 8);
  for (int c = cbeg; c < cend; ++c) {
    int m0 = c * 256;
    int base = n0 - m0 - 256;
    __syncthreads();
    ds[tid] = dry[b * NSMP + m0 + tid];
    for (int k = tid; k < 2568; k += 256) {
      int idx = base + k;
      is[k] = (idx >= 0 && idx < NSMP) ? impulse[b * NSMP + idx] : 0.f;
    }
    __syncthreads();
    float wv[8];
    int kb = tid * 8 + 1;
#pragma unroll
    for (int i = 0; i < 8; ++i) wv[i] = is[kb + i];
#pragma unroll 8
    for (int step = 0; step < 256; ++step) {
      float dv = ds[255 - step];
#pragma unroll
      for (int i = 0; i < 8; ++i) acc[i] += dv * wv[i];
#pragma unroll
      for (int i = 0; i < 7; ++i) wv[i] = wv[i + 1];
      wv[7] = is[kb + 8 + step];
    }
  }
#pragma unroll
  for (int i = 0; i < 8; ++i)
    atomicAdd(&wet[b * NSMP + n0 + tid * 8 + i], acc[i]);
}

// ---------------- out = dry*mix + wet*(1-mix) ----------------
__global__ void out_kernel(const float* __restrict__ dry, const float* __restrict__ wet,
                           const float* __restrict__ mixv, float* __restrict__ out) {
  int b = blockIdx.y;
  int n = blockIdx.x * 256 + threadIdx.x;
  float m = mixv[b];
  float v = dry[b * NSMP + n] * m + wet[b * NSMP + n] * (1.f - m);
  out[b * NSMP + n] = v;
}

extern "C" void kernel_launch(void* const* d_in, const int* in_sizes, int n_in,
                              void* d_out, int out_size, void* d_ws, size_t ws_size,
                              hipStream_t stream) {
  const float* x    = (const float*)d_in[0];
  const float* atoms= (const float*)d_in[1];
  const float* encw = (const float*)d_in[2];
  const float* encb = (const float*)d_in[3];
  const float* upw  = (const float*)d_in[4];
  const float* upb  = (const float*)d_in[5];
  const float* latw = (const float*)d_in[6];
  const float* latb = (const float*)d_in[7];
  const float* rw   = (const float*)d_in[8];
  const float* rb   = (const float*)d_in[9];
  const float* rg   = (const float*)d_in[10];
  const float* rbe  = (const float*)d_in[11];
  const float* rowt = (const float*)d_in[12];
  const float* rob  = (const float*)d_in[13];
  const float* mw   = (const float*)d_in[14];
  const float* mb   = (const float*)d_in[15];
  const float* mg   = (const float*)d_in[16];
  const float* mbe  = (const float*)d_in[17];
  const float* mow  = (const float*)d_in[18];
  const float* mob  = (const float*)d_in[19];
  const float* imps = (const float*)d_in[20];

  float* f    = (float*)d_ws;
  float* h0   = f;                 // 524288
  float* h1   = f + 524288;        // 524288
  float* yacc = f + 1048576;       // 524288  (conv partial accumulator, self-cleaning)
  float* enc  = f + 1572864;       // 131072  (enc partial accumulator, self-cleaning)
  float* dry  = f + 1703936;       // 131072
  float* imp  = f + 1835008;       // 131072
  float* wet  = f + 1966080;       // 131072
  float* room = f + 2097152;       // 32
  float* mixv = f + 2097184;       // 4
  float* vals = f + 2097216;       // 64
  int*   chs  = (int*)(f + 2097280);
  int*   tps  = (int*)(f + 2097344);

  // zero accumulators once (poisoned 0xAA on first call; self-cleaned afterwards)
  hipMemsetAsync(yacc, 0, (524288 + 131072) * sizeof(float), stream);

  stft_kernel<<<512, 256, 0, stream>>>(x, h0);

  // 8 dilated residual conv layers: f32 K-split partial GEMM + fused epilogue
  float* bufs[2] = {h0, h1};
  const int dil[8] = {1, 2, 4, 8, 16, 32, 64, 1};
  dim3 pgrid(16, 8, 4);  // 512 blocks = 2/CU
  for (int l = 0; l < 8; ++l) {
    const float* hin = bufs[l & 1];
    float* hout = bufs[(l + 1) & 1];
    const float* wl = encw + (size_t)l * 1024 * 2048;
    const float* bl = encb + l * 1024;
    switch (dil[l]) {
      case 1:  gemm_partial<2, 1,  2048, 8><<<pgrid, 256, 0, stream>>>(hin, wl, yacc, 1024); break;
      case 2:  gemm_partial<2, 2,  2048, 8><<<pgrid, 256, 0, stream>>>(hin, wl, yacc, 1024); break;
      case 4:  gemm_partial<2, 4,  2048, 8><<<pgrid, 256, 0, stream>>>(hin, wl, yacc, 1024); break;
      case 8:  gemm_partial<2, 8,  2048, 8><<<pgrid, 256, 0, stream>>>(hin, wl, yacc, 1024); break;
      case 16: gemm_partial<2, 16, 2048, 8><<<pgrid, 256, 0, stream>>>(hin, wl, yacc, 1024); break;
      case 32: gemm_partial<2, 32, 2048, 8><<<pgrid, 256, 0, stream>>>(hin, wl, yacc, 1024); break;
      case 64: gemm_partial<2, 64, 2048, 8><<<pgrid, 256, 0, stream>>>(hin, wl, yacc, 1024); break;
    }
    conv_epilogue<<<512, 256, 0, stream>>>(yacc, hin, bl, hout);
  }
  // final h in h0

  dense_mlp_kernel<<<4, 256, 0, stream>>>(h0, latw, latb, rw, rb, rg, rbe, rowt, rob,
                                          mw, mb, mg, mbe, mow, mob, room, mixv);
  // enc partial (bias folded into topk)
  gemm_partial<1, 0, 1024, 8><<<dim3(4, 8, 4), 256, 0, stream>>>(h0, upw, enc, 256);
  topk_kernel<<<4, 256, 0, stream>>>(enc, upb, vals, chs, tps);
  dry_kernel<<<dim3(128, 4), 256, 0, stream>>>(atoms, vals, chs, tps, dry);
  impulse_kernel<<<dim3(128, 4), 256, 0, stream>>>(imps, room, imp);
  hipMemsetAsync(wet, 0, (size_t)NB * NSMP * sizeof(float), stream);
  wet_kernel<<<dim3(16, 16, 4), 256, 0, stream>>>(dry, imp, wet);
  out_kernel<<<dim3(128, 4), 256, 0, stream>>>(dry, wet, mixv, (float*)d_out);
}

// Round 5
// 791.440 us; speedup vs baseline: 3.3127x; 1.9861x over previous
//
#include <hip/hip_runtime.h>
#include <hip/hip_bf16.h>
#include <math.h>

#define NSMP 32768
#define NFR 128
#define NCH 1024
#define NB 4

// ---------------- STFT: one block per (batch, frame); 2048-pt radix-2 FFT in LDS ----------------
__global__ __launch_bounds__(256) void stft_kernel(const float* __restrict__ x,
                                                   float* __restrict__ h) {
  __shared__ float re[2048];
  __shared__ float im[2048];
  int bid = blockIdx.x;
  int b = bid >> 7;
  int f = bid & 127;
  int tid = threadIdx.x;
  const float TWO_PI = 6.28318530717958647692f;
  for (int i = tid; i < 2048; i += 256) {
    int rev = (int)(__brev((unsigned)i) >> 21);
    int pos = f * 256 + rev;
    float v = (pos < NSMP) ? x[b * NSMP + pos] : 0.f;
    float w = 0.5f - 0.5f * cosf(TWO_PI * (float)rev / 2047.0f);  // jnp.hanning(2048)
    re[i] = v * w;
    im[i] = 0.f;
  }
  __syncthreads();
  for (int s = 0; s < 11; ++s) {
    int half = 1 << s;
    for (int q = 0; q < 4; ++q) {
      int bi = tid + q * 256;
      int j = bi & (half - 1);
      int i0 = ((bi >> s) << (s + 1)) | j;
      int i1 = i0 + half;
      float ang = -3.14159265358979323846f * (float)j / (float)half;
      float sn, cs;
      sincosf(ang, &sn, &cs);
      float ur = re[i0], ui = im[i0];
      float vr = re[i1], vi = im[i1];
      float tr = vr * cs - vi * sn;
      float ti = vr * sn + vi * cs;
      re[i0] = ur + tr; im[i0] = ui + ti;
      re[i1] = ur - tr; im[i1] = ui - ti;
    }
    __syncthreads();
  }
  for (int k = tid; k < 1024; k += 256) {
    float m = sqrtf(re[k] * re[k] + im[k] * im[k]);
    h[(b * NCH + k) * NFR + f] = m;  // already transposed: (b, ch=bin, t=frame)
  }
}

// ---------------- f32 GEMM, K-split into partial buffers (no atomics) ----------------
// yp[s][b][o][t] = sum_{k in slice s} W[o][k] * B[k][t]
//   TAPS==2: k=2c+tap, B[k][t] = h[c][t+tap*D] (0 past NFR)   TAPS==1: B[k][t]=h[k][t]
// Block: 128 o x 128 t, 256 thr, 8x8 acc/thread (4+4 split, stride-64 halves).
template <int TAPS, int D, int KTOT, int SPLIT, int MROWS>
__global__ __launch_bounds__(256) void gemm_f32(const float* __restrict__ hin,
                                                const float* __restrict__ W,
                                                float* __restrict__ yp) {
  __shared__ float As[64][132];  // [kk][o]
  __shared__ float Bs[64][132];  // [kk][t]
  int tid = threadIdx.x;
  int og = blockIdx.x * 128;
  int b = blockIdx.y;
  int s = blockIdx.z;
  const float* hb = hin + (size_t)b * (NCH * NFR);
  int tx = tid & 15;   // t quad
  int ty = tid >> 4;   // o quad
  float acc[8][8] = {};
  const int KS = KTOT / SPLIT;  // 256
  for (int kt = 0; kt < KS / 64; ++kt) {
    int k0 = s * KS + kt * 64;
    __syncthreads();
    // ---- stage A transposed: As[kk][o] = W[og+o][k0+kk] ----
    {
      int r = tid >> 1;
      int half = (tid & 1) * 32;
      const float4* src = (const float4*)(W + (size_t)(og + r) * KTOT + k0 + half);
#pragma unroll
      for (int q = 0; q < 8; ++q) {
        float4 v = src[q];
        As[half + 4 * q + 0][r] = v.x;
        As[half + 4 * q + 1][r] = v.y;
        As[half + 4 * q + 2][r] = v.z;
        As[half + 4 * q + 3][r] = v.w;
      }
    }
    // ---- stage B: Bs[kk][t] ----
    {
      int r = tid >> 2;
      int tq = (tid & 3) * 32;
      if (TAPS == 2) {
        int c = (k0 + r) >> 1;
        int sh = (r & 1) * D;
        const float* src = hb + (size_t)c * NFR + sh;
#pragma unroll
        for (int j = 0; j < 32; ++j) {
          int t = tq + j;
          Bs[r][t] = (t + sh < NFR) ? src[t] : 0.f;
        }
      } else {
        int c = k0 + r;
        const float4* src = (const float4*)(hb + (size_t)c * NFR + tq);
#pragma unroll
        for (int q = 0; q < 8; ++q) *(float4*)&Bs[r][tq + 4 * q] = src[q];
      }
    }
    __syncthreads();
#pragma unroll 8
    for (int kk = 0; kk < 64; ++kk) {
      float4 a0 = *(const float4*)&As[kk][ty * 4];
      float4 a1 = *(const float4*)&As[kk][ty * 4 + 64];
      float4 b0 = *(const float4*)&Bs[kk][tx * 4];
      float4 b1 = *(const float4*)&Bs[kk][tx * 4 + 64];
      float av[8] = {a0.x, a0.y, a0.z, a0.w, a1.x, a1.y, a1.z, a1.w};
      float bv[8] = {b0.x, b0.y, b0.z, b0.w, b1.x, b1.y, b1.z, b1.w};
#pragma unroll
      for (int i = 0; i < 8; ++i)
#pragma unroll
        for (int j = 0; j < 8; ++j)
          acc[i][j] += av[i] * bv[j];
    }
  }
  float* ypb = yp + (size_t)s * (NB * MROWS * NFR) + (size_t)b * MROWS * NFR;
#pragma unroll
  for (int i = 0; i < 8; ++i) {
    int o = og + ((i < 4) ? (ty * 4 + i) : (64 + ty * 4 + i - 4));
    *(float4*)&ypb[o * NFR + tx * 4] = (float4){acc[i][0], acc[i][1], acc[i][2], acc[i][3]};
    *(float4*)&ypb[o * NFR + tx * 4 + 64] = (float4){acc[i][4], acc[i][5], acc[i][6], acc[i][7]};
  }
}

// ---------------- conv epilogue: hout = hin + lrelu(sum_s yp[s] + bias) ----------------
__global__ __launch_bounds__(256) void conv_epilogue(const float* __restrict__ yp,
                                                     const float* __restrict__ hin,
                                                     const float* __restrict__ bias,
                                                     float* __restrict__ hout) {
  int idx = blockIdx.x * 256 + threadIdx.x;  // float4 index, 131072 total
  int flat = idx * 4;
  int o = (flat >> 7) & 1023;
  float4 y = ((const float4*)yp)[idx];
#pragma unroll
  for (int s = 1; s < 8; ++s) {
    float4 p = ((const float4*)yp)[s * 131072 + idx];
    y.x += p.x; y.y += p.y; y.z += p.z; y.w += p.w;
  }
  float4 hv = ((const float4*)hin)[idx];
  float bv = bias[o];
  float4 r;
  float v;
  v = y.x + bv; r.x = hv.x + ((v > 0.f) ? v : 0.2f * v);
  v = y.y + bv; r.y = hv.y + ((v > 0.f) ? v : 0.2f * v);
  v = y.z + bv; r.z = hv.z + ((v > 0.f) ? v : 0.2f * v);
  v = y.w + bv; r.w = hv.w + ((v > 0.f) ? v : 0.2f * v);
  ((float4*)hout)[idx] = r;
}

// ---------------- z-mean, dense latent, unit-norm, room & mix MLP heads ----------------
__global__ __launch_bounds__(256) void dense_mlp_kernel(
    const float* __restrict__ h,
    const float* __restrict__ latw, const float* __restrict__ latb,
    const float* __restrict__ rw, const float* __restrict__ rb,
    const float* __restrict__ rg, const float* __restrict__ rbe,
    const float* __restrict__ rowt, const float* __restrict__ rob,
    const float* __restrict__ mw, const float* __restrict__ mb,
    const float* __restrict__ mg, const float* __restrict__ mbe,
    const float* __restrict__ mow, const float* __restrict__ mob,
    float* __restrict__ room, float* __restrict__ mixv) {
  __shared__ float z[1024];
  int b = blockIdx.x;
  int tid = threadIdx.x;
  const float* hb = h + b * NCH * NFR;
  for (int c = tid; c < 1024; c += 256) {
    float s = 0.f;
    const float* r = hb + c * NFR;
#pragma unroll 8
    for (int t = 0; t < NFR; ++t) s += r[t];
    z[c] = s * (1.f / 128.f);
  }
  __syncthreads();
  if (tid >= 64) return;   // one wave does the tiny MLPs; no barriers below
  int j = tid & 15;
  int p = tid >> 4;        // 4 partial-sum groups
  float dsum = 0.f;
  for (int c = p * 256; c < p * 256 + 256; ++c)
    dsum += z[c] * latw[c * 16 + j];
  dsum += __shfl_xor(dsum, 16);
  dsum += __shfl_xor(dsum, 32);
  float dj = dsum + latb[j];
  float sq = dj * dj;
  sq += __shfl_xor(sq, 1, 16);
  sq += __shfl_xor(sq, 2, 16);
  sq += __shfl_xor(sq, 4, 16);
  sq += __shfl_xor(sq, 8, 16);
  float a = dj / (sqrtf(sq) + 1e-8f);   // unit_norm(dense)

  const float* W = rw;  const float* Bb = rb;
  const float* G = rg;  const float* Be = rbe;
  for (int which = 0; which < 2; ++which) {
    float v = a;
    for (int l = 0; l < 3; ++l) {
      float accv = Bb[l * 16 + j];
      for (int k = 0; k < 16; ++k) {
        float ak = __shfl(v, (tid & 48) | k);
        accv += ak * W[(l * 16 + k) * 16 + j];
      }
      float mu = accv;
      mu += __shfl_xor(mu, 1, 16); mu += __shfl_xor(mu, 2, 16);
      mu += __shfl_xor(mu, 4, 16); mu += __shfl_xor(mu, 8, 16);
      mu *= (1.f / 16.f);
      float dv = accv - mu;
      float var = dv * dv;
      var += __shfl_xor(var, 1, 16); var += __shfl_xor(var, 2, 16);
      var += __shfl_xor(var, 4, 16); var += __shfl_xor(var, 8, 16);
      var *= (1.f / 16.f);
      float xn = dv * rsqrtf(var + 1e-5f) * G[l * 16 + j] + Be[l * 16 + j];
      v = (xn > 0.f) ? xn : 0.2f * xn;
    }
    if (which == 0) {
      int r = tid & 7;
      float logit = rob[r];
      for (int k = 0; k < 16; ++k) {
        float ak = __shfl(v, (tid & 48) | k);
        logit += ak * rowt[k * 8 + r];
      }
      float mx = logit;
      mx = fmaxf(mx, __shfl_xor(mx, 1, 8));
      mx = fmaxf(mx, __shfl_xor(mx, 2, 8));
      mx = fmaxf(mx, __shfl_xor(mx, 4, 8));
      float e = expf(logit - mx);
      float se = e;
      se += __shfl_xor(se, 1, 8);
      se += __shfl_xor(se, 2, 8);
      se += __shfl_xor(se, 4, 8);
      if (tid < 8) room[b * 8 + r] = e / se;
      W = mw; Bb = mb; G = mg; Be = mbe;
    } else {
      float logit = mob[0];
      for (int k = 0; k < 16; ++k) {
        float ak = __shfl(v, (tid & 48) | k);
        logit += ak * mow[k];
      }
      if (tid == 0) mixv[b] = 1.f / (1.f + expf(-logit));
    }
  }
}

// ---------------- top-16 (jax tie semantics): register lists + shuffle merge ----------------
// value = sum_{s<4} ep[s] + upb[ch]
__global__ __launch_bounds__(256) void topk_kernel(const float* __restrict__ ep,
                                                   const float* __restrict__ upb,
                                                   float* __restrict__ vals,
                                                   int* __restrict__ chs,
                                                   int* __restrict__ tps) {
  __shared__ float swv[4];
  __shared__ int swi[4];
  int b = blockIdx.x;
  int tid = threadIdx.x;
  const float* e = ep + b * 32768;
  float lv[16];
  int li[16];
#pragma unroll
  for (int q = 0; q < 16; ++q) { lv[q] = -INFINITY; li[q] = 0x7fffffff; }
  for (int i = tid; i < 32768; i += 256) {
    float v = e[i] + e[131072 + i] + e[262144 + i] + e[393216 + i] + upb[i >> 7];
    if (v > lv[15]) {
      float cv = v; int ci = i;
#pragma unroll
      for (int q = 0; q < 16; ++q) {
        if (cv > lv[q]) {
          float tv = lv[q]; int ti = li[q];
          lv[q] = cv; li[q] = ci;
          cv = tv; ci = ti;
        }
      }
    }
  }
  for (int round = 0; round < 16; ++round) {
    float cv = lv[0];
    int ci = li[0];
#pragma unroll
    for (int off = 1; off < 64; off <<= 1) {
      float ov = __shfl_xor(cv, off);
      int oi = __shfl_xor(ci, off);
      if (ov > cv || (ov == cv && oi < ci)) { cv = ov; ci = oi; }
    }
    if ((tid & 63) == 0) { swv[tid >> 6] = cv; swi[tid >> 6] = ci; }
    __syncthreads();
    float wv = swv[0]; int wi = swi[0];
#pragma unroll
    for (int w = 1; w < 4; ++w) {
      float v2 = swv[w]; int i2 = swi[w];
      if (v2 > wv || (v2 == wv && i2 < wi)) { wv = v2; wi = i2; }
    }
    if (tid == 0) {
      // negative winner: reference's top_k picks a zero of `full` instead -> zero event
      vals[b * 16 + round] = (wv > 0.f) ? wv : 0.f;
      chs[b * 16 + round] = wi >> 7;            // i = ch*128 + t
      tps[b * 16 + round] = (wi & 127) * 256;   // sample position t*STEP
    }
    if (li[0] == wi) {  // unique owner pops
#pragma unroll
      for (int q = 0; q < 15; ++q) { lv[q] = lv[q + 1]; li[q] = li[q + 1]; }
      lv[15] = -INFINITY; li[15] = 0x7fffffff;
    }
    __syncthreads();
  }
}

// ---------------- dry = sum of 16 scaled shifted atoms (sparse conv collapsed) ----------------
__global__ void dry_kernel(const float* __restrict__ atoms,
                           const float* __restrict__ vals, const int* __restrict__ chs,
                           const int* __restrict__ tps, float* __restrict__ dry) {
  int b = blockIdx.y;
  int n = blockIdx.x * 256 + threadIdx.x;
  float acc = 0.f;
#pragma unroll 4
  for (int j = 0; j < 16; ++j) {
    float v = vals[b * 16 + j];
    int tp = tps[b * 16 + j];
    int ch = chs[b * 16 + j];
    if (v != 0.f && n >= tp)
      acc += v * atoms[(size_t)ch * NSMP + (n - tp)];
  }
  dry[b * NSMP + n] = acc;
}

// ---------------- impulse = room @ impulses ----------------
__global__ void impulse_kernel(const float* __restrict__ imps,
                               const float* __restrict__ room, float* __restrict__ imp) {
  int b = blockIdx.y;
  int n = blockIdx.x * 256 + threadIdx.x;
  float acc = 0.f;
#pragma unroll
  for (int r = 0; r < 8; ++r)
    acc += room[b * 8 + r] * imps[r * NSMP + n];
  imp[b * NSMP + n] = acc;
}

// ---------------- wet = causal conv, skewed-LDS sliding window, 16 n/thread ----------------
// block: n-tile of 4096 (nt), m-range of 1024 (g), batch b. acc[i] for n = n0 + tid*16 + i.
#define IS(a) is[(a) + ((a) >> 5)]
__global__ __launch_bounds__(256) void wet_kernel(const float* __restrict__ dry,
                                                  const float* __restrict__ impulse,
                                                  float* __restrict__ wet) {
  int g = blockIdx.x;    // m-range [g*1024, g*1024+1024)
  int nt = blockIdx.y;   // n-tile of 4096
  int b = blockIdx.z;
  if (g >= 4 * (nt + 1)) return;  // beyond causal triangle
  __shared__ float is[5280];      // 5120 logical + skew pad
  __shared__ float dsr[1024];     // dry reversed
  int tid = threadIdx.x;
  int n0 = nt * 4096;
  int m0 = g * 1024;
  int base = n0 - m0 - 1023;
  const float* impb = impulse + b * NSMP;
  for (int k = tid; k < 5120; k += 256) {
    int idx = base + k;
    IS(k) = (idx >= 0 && idx < NSMP) ? impb[idx] : 0.f;
  }
  for (int i = tid; i < 1024; i += 256)
    dsr[i] = dry[b * NSMP + m0 + 1023 - i];
  __syncthreads();
  int aw = tid * 16;
  float w[16];
#pragma unroll
  for (int j = 0; j < 16; ++j) w[j] = IS(aw + j);
  float acc[16] = {};
  for (int s0 = 0; s0 < 1024; s0 += 16) {
#pragma unroll
    for (int su = 0; su < 16; su += 4) {
      float4 d4 = *(const float4*)&dsr[s0 + su];
      float dv[4] = {d4.x, d4.y, d4.z, d4.w};
#pragma unroll
      for (int e = 0; e < 4; ++e) {
        float dval = dv[e];
#pragma unroll
        for (int i = 0; i < 16; ++i)
          acc[i] += dval * w[(su + e + i) & 15];
        w[(su + e) & 15] = IS(aw + s0 + su + e + 16);  // slide window
      }
    }
  }
#pragma unroll
  for (int i = 0; i < 16; ++i)
    atomicAdd(&wet[b * NSMP + n0 + aw + i], acc[i]);
}

// ---------------- out = dry*mix + wet*(1-mix) ----------------
__global__ void out_kernel(const float* __restrict__ dry, const float* __restrict__ wet,
                           const float* __restrict__ mixv, float* __restrict__ out) {
  int b = blockIdx.y;
  int n = blockIdx.x * 256 + threadIdx.x;
  float m = mixv[b];
  float v = dry[b * NSMP + n] * m + wet[b * NSMP + n] * (1.f - m);
  out[b * NSMP + n] = v;
}

extern "C" void kernel_launch(void* const* d_in, const int* in_sizes, int n_in,
                              void* d_out, int out_size, void* d_ws, size_t ws_size,
                              hipStream_t stream) {
  const float* x    = (const float*)d_in[0];
  const float* atoms= (const float*)d_in[1];
  const float* encw = (const float*)d_in[2];
  const float* encb = (const float*)d_in[3];
  const float* upw  = (const float*)d_in[4];
  const float* upb  = (const float*)d_in[5];
  const float* latw = (const float*)d_in[6];
  const float* latb = (const float*)d_in[7];
  const float* rw   = (const float*)d_in[8];
  const float* rb   = (const float*)d_in[9];
  const float* rg   = (const float*)d_in[10];
  const float* rbe  = (const float*)d_in[11];
  const float* rowt = (const float*)d_in[12];
  const float* rob  = (const float*)d_in[13];
  const float* mw   = (const float*)d_in[14];
  const float* mb   = (const float*)d_in[15];
  const float* mg   = (const float*)d_in[16];
  const float* mbe  = (const float*)d_in[17];
  const float* mow  = (const float*)d_in[18];
  const float* mob  = (const float*)d_in[19];
  const float* imps = (const float*)d_in[20];

  float* f    = (float*)d_ws;
  float* h0   = f;                 // 524288
  float* h1   = f + 524288;        // 524288
  float* yp   = f + 1048576;       // 8 x 524288 = 4194304 (conv K-split partials)
  float* ep   = yp;                // 4 x 131072 alias (enc partials; used after convs)
  float* dry  = f + 5242880;       // 131072
  float* imp  = f + 5373952;       // 131072
  float* wet  = f + 5505024;       // 131072
  float* room = f + 5636096;       // 32
  float* mixv = f + 5636128;       // 4
  float* vals = f + 5636160;       // 64
  int*   chs  = (int*)(f + 5636224);
  int*   tps  = (int*)(f + 5636288);

  stft_kernel<<<512, 256, 0, stream>>>(x, h0);

  // 8 dilated residual conv layers: f32 K-split GEMM into partials + fused epilogue
  float* bufs[2] = {h0, h1};
  const int dil[8] = {1, 2, 4, 8, 16, 32, 64, 1};
  dim3 cgrid(8, 4, 8);  // 256 blocks, 1/CU
  for (int l = 0; l < 8; ++l) {
    const float* hin = bufs[l & 1];
    float* hout = bufs[(l + 1) & 1];
    const float* wl = encw + (size_t)l * 1024 * 2048;
    const float* bl = encb + l * 1024;
    switch (dil[l]) {
      case 1:  gemm_f32<2, 1,  2048, 8, 1024><<<cgrid, 256, 0, stream>>>(hin, wl, yp); break;
      case 2:  gemm_f32<2, 2,  2048, 8, 1024><<<cgrid, 256, 0, stream>>>(hin, wl, yp); break;
      case 4:  gemm_f32<2, 4,  2048, 8, 1024><<<cgrid, 256, 0, stream>>>(hin, wl, yp); break;
      case 8:  gemm_f32<2, 8,  2048, 8, 1024><<<cgrid, 256, 0, stream>>>(hin, wl, yp); break;
      case 16: gemm_f32<2, 16, 2048, 8, 1024><<<cgrid, 256, 0, stream>>>(hin, wl, yp); break;
      case 32: gemm_f32<2, 32, 2048, 8, 1024><<<cgrid, 256, 0, stream>>>(hin, wl, yp); break;
      case 64: gemm_f32<2, 64, 2048, 8, 1024><<<cgrid, 256, 0, stream>>>(hin, wl, yp); break;
    }
    conv_epilogue<<<512, 256, 0, stream>>>(yp, hin, bl, hout);
  }
  // final h in h0

  dense_mlp_kernel<<<4, 256, 0, stream>>>(h0, latw, latb, rw, rb, rg, rbe, rowt, rob,
                                          mw, mb, mg, mbe, mow, mob, room, mixv);
  // enc = up_w @ h (K=1024, SPLIT=4); bias folded into topk
  gemm_f32<1, 0, 1024, 4, 256><<<dim3(2, 4, 4), 256, 0, stream>>>(h0, upw, ep);
  topk_kernel<<<4, 256, 0, stream>>>(ep, upb, vals, chs, tps);
  dry_kernel<<<dim3(128, 4), 256, 0, stream>>>(atoms, vals, chs, tps, dry);
  impulse_kernel<<<dim3(128, 4), 256, 0, stream>>>(imps, room, imp);
  hipMemsetAsync(wet, 0, (size_t)NB * NSMP * sizeof(float), stream);
  wet_kernel<<<dim3(32, 8, 4), 256, 0, stream>>>(dry, imp, wet);
  out_kernel<<<dim3(128, 4), 256, 0, stream>>>(dry, wet, mixv, (float*)d_out);
}

// Round 6
// 666.298 us; speedup vs baseline: 3.9349x; 1.1878x over previous
//
#include <hip/hip_runtime.h>
#include <hip/hip_bf16.h>
#include <math.h>

#define NSMP 32768
#define NFR 128
#define NCH 1024
#define NB 4

// ---------------- STFT: one block per (batch, frame); 2048-pt radix-2 FFT in LDS ----------------
__global__ __launch_bounds__(256) void stft_kernel(const float* __restrict__ x,
                                                   float* __restrict__ h) {
  __shared__ float re[2048];
  __shared__ float im[2048];
  __shared__ float twr[1024];
  __shared__ float twi[1024];
  int bid = blockIdx.x;
  int b = bid >> 7;
  int f = bid & 127;
  int tid = threadIdx.x;
  const float TWO_PI = 6.28318530717958647692f;
  for (int k = tid; k < 1024; k += 256) {
    float ang = -TWO_PI * (float)k / 2048.0f;
    float sn, cs;
    sincosf(ang, &sn, &cs);
    twr[k] = cs; twi[k] = sn;
  }
  for (int i = tid; i < 2048; i += 256) {
    int rev = (int)(__brev((unsigned)i) >> 21);
    int pos = f * 256 + rev;
    float v = (pos < NSMP) ? x[b * NSMP + pos] : 0.f;
    float w = 0.5f - 0.5f * cosf(TWO_PI * (float)rev / 2047.0f);  // jnp.hanning(2048)
    re[i] = v * w;
    im[i] = 0.f;
  }
  __syncthreads();
  for (int s = 0; s < 11; ++s) {
    for (int q = 0; q < 4; ++q) {
      int bi = tid + q * 256;
      int half = 1 << s;
      int j = bi & (half - 1);
      int i0 = ((bi >> s) << (s + 1)) | j;
      int i1 = i0 + half;
      int ti = j << (10 - s);
      float cs = twr[ti], sn = twi[ti];
      float ur = re[i0], ui = im[i0];
      float vr = re[i1], vi = im[i1];
      float tr = vr * cs - vi * sn;
      float tti = vr * sn + vi * cs;
      re[i0] = ur + tr; im[i0] = ui + tti;
      re[i1] = ur - tr; im[i1] = ui - tti;
    }
    __syncthreads();
  }
  for (int k = tid; k < 1024; k += 256) {
    float m = sqrtf(re[k] * re[k] + im[k] * im[k]);
    h[(b * NCH + k) * NFR + f] = m;  // already transposed: (b, ch=bin, t=frame)
  }
}

// ---------------- f32 GEMM, K-split into partial buffers (no atomics) ----------------
// yp[s][b][o][t] = sum_{k in slice s} W[o][k] * B[k][t]
//   TAPS==2: k=2c+tap, B[k][t] = h[c][t+tap*D] (0 past NFR)   TAPS==1: B[k][t]=h[k][t]
// Block: 64 o x 128 t, 256 thr, 4x8 acc/thread. 2 blocks/CU.
template <int TAPS, int D, int KTOT, int SPLIT, int MROWS>
__global__ __launch_bounds__(256, 2) void gemm_f32(const float* __restrict__ hin,
                                                   const float* __restrict__ W,
                                                   float* __restrict__ yp) {
  __shared__ float As[64][68];   // [kk][o], col XOR-swizzled by ((kk>>4)&1)<<2
  __shared__ float Bs[64][132];  // [kk][t]
  int tid = threadIdx.x;
  int og = blockIdx.x * 64;
  int b = blockIdx.y;
  int s = blockIdx.z;
  const float* hb = hin + (size_t)b * (NCH * NFR);
  int tx = tid & 15;   // t quad
  int ty = tid >> 4;   // o quad (0..15 -> 64 o)
  float acc[4][8] = {};
  const int KS = KTOT / SPLIT;
  for (int kt = 0; kt < KS / 64; ++kt) {
    int k0 = s * KS + kt * 64;
    __syncthreads();
    // ---- stage A transposed: As[kk][o'] = W[og+o][k0+kk], o' = o ^ flip(kk) ----
    {
      int r = tid >> 2;             // o row 0..63
      int seg = (tid & 3) * 16;     // k segment
      const float4* src = (const float4*)(W + (size_t)(og + r) * KTOT + k0 + seg);
#pragma unroll
      for (int q = 0; q < 4; ++q) {
        float4 v = src[q];
        int row = seg + 4 * q;
#pragma unroll
        for (int i = 0; i < 4; ++i) {
          int rr = row + i;
          int col = r ^ (((rr >> 4) & 1) << 2);
          float val = (i == 0) ? v.x : (i == 1) ? v.y : (i == 2) ? v.z : v.w;
          As[rr][col] = val;
        }
      }
    }
    // ---- stage B: Bs[kk][t] ----
    {
      int r = tid >> 2;
      int tq = (tid & 3) * 32;
      if (TAPS == 2) {
        int c = (k0 + r) >> 1;
        int sh = (r & 1) * D;
        const float* src = hb + (size_t)c * NFR + sh;
#pragma unroll
        for (int q = 0; q < 8; ++q) {
          int t0 = tq + 4 * q;
          if (((D & 3) == 0 || sh == 0) && (t0 + 3 + sh < NFR)) {
            *(float4*)&Bs[r][t0] = *(const float4*)(src + t0);
          } else {
#pragma unroll
            for (int j = 0; j < 4; ++j)
              Bs[r][t0 + j] = (t0 + j + sh < NFR) ? src[t0 + j] : 0.f;
          }
        }
      } else {
        int c = k0 + r;
        const float4* src = (const float4*)(hb + (size_t)c * NFR + tq);
#pragma unroll
        for (int q = 0; q < 8; ++q) *(float4*)&Bs[r][tq + 4 * q] = src[q];
      }
    }
    __syncthreads();
#pragma unroll 8
    for (int kk = 0; kk < 64; ++kk) {
      int ca = (ty * 4) ^ (((kk >> 4) & 1) << 2);
      float4 a0 = *(const float4*)&As[kk][ca];
      float4 b0 = *(const float4*)&Bs[kk][tx * 4];
      float4 b1 = *(const float4*)&Bs[kk][tx * 4 + 64];
      float av[4] = {a0.x, a0.y, a0.z, a0.w};
      float bv[8] = {b0.x, b0.y, b0.z, b0.w, b1.x, b1.y, b1.z, b1.w};
#pragma unroll
      for (int i = 0; i < 4; ++i)
#pragma unroll
        for (int j = 0; j < 8; ++j)
          acc[i][j] += av[i] * bv[j];
    }
  }
  float* ypb = yp + (size_t)s * (NB * MROWS * NFR) + (size_t)b * MROWS * NFR;
#pragma unroll
  for (int i = 0; i < 4; ++i) {
    int o = og + ty * 4 + i;
    *(float4*)&ypb[o * NFR + tx * 4] = (float4){acc[i][0], acc[i][1], acc[i][2], acc[i][3]};
    *(float4*)&ypb[o * NFR + tx * 4 + 64] = (float4){acc[i][4], acc[i][5], acc[i][6], acc[i][7]};
  }
}

// ---------------- conv epilogue: hout = hin + lrelu(sum_s yp[s] + bias) ----------------
__global__ __launch_bounds__(256) void conv_epilogue(const float* __restrict__ yp,
                                                     const float* __restrict__ hin,
                                                     const float* __restrict__ bias,
                                                     float* __restrict__ hout) {
  int idx = blockIdx.x * 256 + threadIdx.x;  // float4 index, 131072 total
  int flat = idx * 4;
  int o = (flat >> 7) & 1023;
  float4 y = ((const float4*)yp)[idx];
#pragma unroll
  for (int s = 1; s < 8; ++s) {
    float4 p = ((const float4*)yp)[s * 131072 + idx];
    y.x += p.x; y.y += p.y; y.z += p.z; y.w += p.w;
  }
  float4 hv = ((const float4*)hin)[idx];
  float bv = bias[o];
  float4 r;
  float v;
  v = y.x + bv; r.x = hv.x + ((v > 0.f) ? v : 0.2f * v);
  v = y.y + bv; r.y = hv.y + ((v > 0.f) ? v : 0.2f * v);
  v = y.z + bv; r.z = hv.z + ((v > 0.f) ? v : 0.2f * v);
  v = y.w + bv; r.w = hv.w + ((v > 0.f) ? v : 0.2f * v);
  ((float4*)hout)[idx] = r;
}

// ---------------- z-mean, dense latent, unit-norm, room & mix MLP heads ----------------
__global__ __launch_bounds__(256) void dense_mlp_kernel(
    const float* __restrict__ h,
    const float* __restrict__ latw, const float* __restrict__ latb,
    const float* __restrict__ rw, const float* __restrict__ rb,
    const float* __restrict__ rg, const float* __restrict__ rbe,
    const float* __restrict__ rowt, const float* __restrict__ rob,
    const float* __restrict__ mw, const float* __restrict__ mb,
    const float* __restrict__ mg, const float* __restrict__ mbe,
    const float* __restrict__ mow, const float* __restrict__ mob,
    float* __restrict__ room, float* __restrict__ mixv) {
  __shared__ float z[1024];
  int b = blockIdx.x;
  int tid = threadIdx.x;
  const float* hb = h + b * NCH * NFR;
  for (int c = tid; c < 1024; c += 256) {
    float s = 0.f;
    const float* r = hb + c * NFR;
#pragma unroll 8
    for (int t = 0; t < NFR; ++t) s += r[t];
    z[c] = s * (1.f / 128.f);
  }
  __syncthreads();
  if (tid >= 64) return;   // one wave does the tiny MLPs; no barriers below
  int j = tid & 15;
  int p = tid >> 4;        // 4 partial-sum groups
  float dsum = 0.f;
  for (int c = p * 256; c < p * 256 + 256; ++c)
    dsum += z[c] * latw[c * 16 + j];
  dsum += __shfl_xor(dsum, 16);
  dsum += __shfl_xor(dsum, 32);
  float dj = dsum + latb[j];
  float sq = dj * dj;
  sq += __shfl_xor(sq, 1, 16);
  sq += __shfl_xor(sq, 2, 16);
  sq += __shfl_xor(sq, 4, 16);
  sq += __shfl_xor(sq, 8, 16);
  float a = dj / (sqrtf(sq) + 1e-8f);   // unit_norm(dense)

  const float* W = rw;  const float* Bb = rb;
  const float* G = rg;  const float* Be = rbe;
  for (int which = 0; which < 2; ++which) {
    float v = a;
    for (int l = 0; l < 3; ++l) {
      float accv = Bb[l * 16 + j];
      for (int k = 0; k < 16; ++k) {
        float ak = __shfl(v, (tid & 48) | k);
        accv += ak * W[(l * 16 + k) * 16 + j];
      }
      float mu = accv;
      mu += __shfl_xor(mu, 1, 16); mu += __shfl_xor(mu, 2, 16);
      mu += __shfl_xor(mu, 4, 16); mu += __shfl_xor(mu, 8, 16);
      mu *= (1.f / 16.f);
      float dv = accv - mu;
      float var = dv * dv;
      var += __shfl_xor(var, 1, 16); var += __shfl_xor(var, 2, 16);
      var += __shfl_xor(var, 4, 16); var += __shfl_xor(var, 8, 16);
      var *= (1.f / 16.f);
      float xn = dv * rsqrtf(var + 1e-5f) * G[l * 16 + j] + Be[l * 16 + j];
      v = (xn > 0.f) ? xn : 0.2f * xn;
    }
    if (which == 0) {
      int r = tid & 7;
      float logit = rob[r];
      for (int k = 0; k < 16; ++k) {
        float ak = __shfl(v, (tid & 48) | k);
        logit += ak * rowt[k * 8 + r];
      }
      float mx = logit;
      mx = fmaxf(mx, __shfl_xor(mx, 1, 8));
      mx = fmaxf(mx, __shfl_xor(mx, 2, 8));
      mx = fmaxf(mx, __shfl_xor(mx, 4, 8));
      float e = expf(logit - mx);
      float se = e;
      se += __shfl_xor(se, 1, 8);
      se += __shfl_xor(se, 2, 8);
      se += __shfl_xor(se, 4, 8);
      if (tid < 8) room[b * 8 + r] = e / se;
      W = mw; Bb = mb; G = mg; Be = mbe;
    } else {
      float logit = mob[0];
      for (int k = 0; k < 16; ++k) {
        float ak = __shfl(v, (tid & 48) | k);
        logit += ak * mow[k];
      }
      if (tid == 0) mixv[b] = 1.f / (1.f + expf(-logit));
    }
  }
}

// ---------------- top-16 (jax tie semantics): register lists + shuffle merge ----------------
// value = sum_{s<4} ep[s] + upb[ch]
__global__ __launch_bounds__(256) void topk_kernel(const float* __restrict__ ep,
                                                   const float* __restrict__ upb,
                                                   float* __restrict__ vals,
                                                   int* __restrict__ chs,
                                                   int* __restrict__ tps) {
  __shared__ float swv[4];
  __shared__ int swi[4];
  int b = blockIdx.x;
  int tid = threadIdx.x;
  const float* e = ep + b * 32768;
  float lv[16];
  int li[16];
#pragma unroll
  for (int q = 0; q < 16; ++q) { lv[q] = -INFINITY; li[q] = 0x7fffffff; }
  for (int i = tid; i < 32768; i += 256) {
    float v = e[i] + e[131072 + i] + e[262144 + i] + e[393216 + i] + upb[i >> 7];
    if (v > lv[15]) {
      float cv = v; int ci = i;
#pragma unroll
      for (int q = 0; q < 16; ++q) {
        if (cv > lv[q]) {
          float tv = lv[q]; int ti = li[q];
          lv[q] = cv; li[q] = ci;
          cv = tv; ci = ti;
        }
      }
    }
  }
  for (int round = 0; round < 16; ++round) {
    float cv = lv[0];
    int ci = li[0];
#pragma unroll
    for (int off = 1; off < 64; off <<= 1) {
      float ov = __shfl_xor(cv, off);
      int oi = __shfl_xor(ci, off);
      if (ov > cv || (ov == cv && oi < ci)) { cv = ov; ci = oi; }
    }
    if ((tid & 63) == 0) { swv[tid >> 6] = cv; swi[tid >> 6] = ci; }
    __syncthreads();
    float wv = swv[0]; int wi = swi[0];
#pragma unroll
    for (int w = 1; w < 4; ++w) {
      float v2 = swv[w]; int i2 = swi[w];
      if (v2 > wv || (v2 == wv && i2 < wi)) { wv = v2; wi = i2; }
    }
    if (tid == 0) {
      // negative winner: reference's top_k picks a zero of `full` instead -> zero event
      vals[b * 16 + round] = (wv > 0.f) ? wv : 0.f;
      chs[b * 16 + round] = wi >> 7;            // i = ch*128 + t
      tps[b * 16 + round] = (wi & 127) * 256;   // sample position t*STEP
    }
    if (li[0] == wi) {  // unique owner pops
#pragma unroll
      for (int q = 0; q < 15; ++q) { lv[q] = lv[q + 1]; li[q] = li[q + 1]; }
      lv[15] = -INFINITY; li[15] = 0x7fffffff;
    }
    __syncthreads();
  }
}

// ---------------- dry = sum of 16 scaled shifted atoms (sparse conv collapsed) ----------------
__global__ void dry_kernel(const float* __restrict__ atoms,
                           const float* __restrict__ vals, const int* __restrict__ chs,
                           const int* __restrict__ tps, float* __restrict__ dry) {
  int b = blockIdx.y;
  int n = blockIdx.x * 256 + threadIdx.x;
  float acc = 0.f;
#pragma unroll 4
  for (int j = 0; j < 16; ++j) {
    float v = vals[b * 16 + j];
    int tp = tps[b * 16 + j];
    int ch = chs[b * 16 + j];
    if (v != 0.f && n >= tp)
      acc += v * atoms[(size_t)ch * NSMP + (n - tp)];
  }
  dry[b * NSMP + n] = acc;
}

// ---------------- impulse = room @ impulses ----------------
__global__ void impulse_kernel(const float* __restrict__ imps,
                               const float* __restrict__ room, float* __restrict__ imp) {
  int b = blockIdx.y;
  int n = blockIdx.x * 256 + threadIdx.x;
  float acc = 0.f;
#pragma unroll
  for (int r = 0; r < 8; ++r)
    acc += room[b * 8 + r] * imps[r * NSMP + n];
  imp[b * NSMP + n] = acc;
}

// ---------------- wet partials: block (s,nt) computes slice-s contribution to n-tile nt ----------------
// wp[s][b][n] = sum_{m in [s*2048,(s+1)*2048)} dry[m] * impulse[n-m], no atomics.
#define IS(a) is[(a) + ((a) >> 5)]
__global__ __launch_bounds__(256) void wet_kernel(const float* __restrict__ dry,
                                                  const float* __restrict__ impulse,
                                                  float* __restrict__ wp) {
  int s = blockIdx.x;    // m-slice
  int nt = blockIdx.y;   // n-tile
  int b = blockIdx.z;
  if (s > nt) return;    // causal
  __shared__ float is[4224];   // 4096 logical + skew
  __shared__ float dsr[2048];  // dry slice reversed
  int tid = threadIdx.x;
  int n0 = nt * 2048;
  int m0 = s * 2048;
  int base = n0 - m0 - 2047;
  const float* impb = impulse + b * NSMP;
  for (int k = tid; k < 4096; k += 256) {
    int idx = base + k;
    IS(k) = (idx >= 0 && idx < NSMP) ? impb[idx] : 0.f;
  }
  for (int i = tid; i < 2048; i += 256)
    dsr[i] = dry[b * NSMP + m0 + 2047 - i];
  __syncthreads();
  int aw = tid * 8;
  float w[8];
#pragma unroll
  for (int j = 0; j < 8; ++j) w[j] = IS(aw + j);
  float acc[8] = {};
  for (int jb = 0; jb < 2048; jb += 8) {
    float4 d0 = *(const float4*)&dsr[jb];
    float4 d1 = *(const float4*)&dsr[jb + 4];
    float dv[8] = {d0.x, d0.y, d0.z, d0.w, d1.x, d1.y, d1.z, d1.w};
#pragma unroll
    for (int e = 0; e < 8; ++e) {
      float dval = dv[e];
#pragma unroll
      for (int i = 0; i < 8; ++i)
        acc[i] += dval * w[(e + i) & 7];
      w[e] = IS(aw + jb + e + 8);  // slide window (static index)
    }
  }
  float* dst = wp + (size_t)s * (NB * NSMP) + (size_t)b * NSMP + n0 + aw;
  *(float4*)dst = (float4){acc[0], acc[1], acc[2], acc[3]};
  *(float4*)(dst + 4) = (float4){acc[4], acc[5], acc[6], acc[7]};
}

// ---------------- out = dry*mix + (sum_s wp[s])*(1-mix) ----------------
__global__ void out_kernel(const float* __restrict__ dry, const float* __restrict__ wp,
                           const float* __restrict__ mixv, float* __restrict__ out) {
  int b = blockIdx.y;
  int n = blockIdx.x * 256 + threadIdx.x;
  float m = mixv[b];
  float wv = 0.f;
  int smax = n >> 11;  // uniform per block (256 | 2048)
  for (int s = 0; s <= smax; ++s)
    wv += wp[(size_t)s * (NB * NSMP) + b * NSMP + n];
  out[b * NSMP + n] = dry[b * NSMP + n] * m + wv * (1.f - m);
}

extern "C" void kernel_launch(void* const* d_in, const int* in_sizes, int n_in,
                              void* d_out, int out_size, void* d_ws, size_t ws_size,
                              hipStream_t stream) {
  const float* x    = (const float*)d_in[0];
  const float* atoms= (const float*)d_in[1];
  const float* encw = (const float*)d_in[2];
  const float* encb = (const float*)d_in[3];
  const float* upw  = (const float*)d_in[4];
  const float* upb  = (const float*)d_in[5];
  const float* latw = (const float*)d_in[6];
  const float* latb = (const float*)d_in[7];
  const float* rw   = (const float*)d_in[8];
  const float* rb   = (const float*)d_in[9];
  const float* rg   = (const float*)d_in[10];
  const float* rbe  = (const float*)d_in[11];
  const float* rowt = (const float*)d_in[12];
  const float* rob  = (const float*)d_in[13];
  const float* mw   = (const float*)d_in[14];
  const float* mb   = (const float*)d_in[15];
  const float* mg   = (const float*)d_in[16];
  const float* mbe  = (const float*)d_in[17];
  const float* mow  = (const float*)d_in[18];
  const float* mob  = (const float*)d_in[19];
  const float* imps = (const float*)d_in[20];

  float* f    = (float*)d_ws;
  float* h0   = f;                 // 524288
  float* h1   = f + 524288;        // 524288
  float* yp   = f + 1048576;       // 8 x 524288 = 4194304 (conv K-split partials)
  float* ep   = yp;                // 4 x 131072 alias (enc partials; used after convs)
  float* wp   = yp + 524288;       // 16 x 131072 alias (wet partials; used after enc/topk)
  float* dry  = f + 5242880;       // 131072
  float* imp  = f + 5373952;       // 131072
  float* room = f + 5636096;       // 32
  float* mixv = f + 5636128;       // 4
  float* vals = f + 5636160;       // 64
  int*   chs  = (int*)(f + 5636224);
  int*   tps  = (int*)(f + 5636288);

  stft_kernel<<<512, 256, 0, stream>>>(x, h0);

  // 8 dilated residual conv layers: f32 K-split GEMM into partials + fused epilogue
  float* bufs[2] = {h0, h1};
  const int dil[8] = {1, 2, 4, 8, 16, 32, 64, 1};
  dim3 cgrid(16, 4, 8);  // 512 blocks, 2/CU
  for (int l = 0; l < 8; ++l) {
    const float* hin = bufs[l & 1];
    float* hout = bufs[(l + 1) & 1];
    const float* wl = encw + (size_t)l * 1024 * 2048;
    const float* bl = encb + l * 1024;
    switch (dil[l]) {
      case 1:  gemm_f32<2, 1,  2048, 8, 1024><<<cgrid, 256, 0, stream>>>(hin, wl, yp); break;
      case 2:  gemm_f32<2, 2,  2048, 8, 1024><<<cgrid, 256, 0, stream>>>(hin, wl, yp); break;
      case 4:  gemm_f32<2, 4,  2048, 8, 1024><<<cgrid, 256, 0, stream>>>(hin, wl, yp); break;
      case 8:  gemm_f32<2, 8,  2048, 8, 1024><<<cgrid, 256, 0, stream>>>(hin, wl, yp); break;
      case 16: gemm_f32<2, 16, 2048, 8, 1024><<<cgrid, 256, 0, stream>>>(hin, wl, yp); break;
      case 32: gemm_f32<2, 32, 2048, 8, 1024><<<cgrid, 256, 0, stream>>>(hin, wl, yp); break;
      case 64: gemm_f32<2, 64, 2048, 8, 1024><<<cgrid, 256, 0, stream>>>(hin, wl, yp); break;
    }
    conv_epilogue<<<512, 256, 0, stream>>>(yp, hin, bl, hout);
  }
  // final h in h0

  dense_mlp_kernel<<<4, 256, 0, stream>>>(h0, latw, latb, rw, rb, rg, rbe, rowt, rob,
                                          mw, mb, mg, mbe, mow, mob, room, mixv);
  // enc = up_w @ h (K=1024, SPLIT=4); bias folded into topk
  gemm_f32<1, 0, 1024, 4, 256><<<dim3(4, 4, 4), 256, 0, stream>>>(h0, upw, ep);
  topk_kernel<<<4, 256, 0, stream>>>(ep, upb, vals, chs, tps);
  dry_kernel<<<dim3(128, 4), 256, 0, stream>>>(atoms, vals, chs, tps, dry);
  impulse_kernel<<<dim3(128, 4), 256, 0, stream>>>(imps, room, imp);
  wet_kernel<<<dim3(16, 16, 4), 256, 0, stream>>>(dry, imp, wp);
  out_kernel<<<dim3(128, 4), 256, 0, stream>>>(dry, wp, mixv, (float*)d_out);
}